// Round 1
// baseline (2410.642 us; speedup 1.0000x reference)
//
#include <hip/hip_runtime.h>

#define B_   8
#define L_   24
#define HPL_ 32
#define HID_ 10
#define N_   (L_*HPL_)   // 768
#define HW_  4096        // 64*64
#define NCH_ 96          // 3*HPL
#define NO_  64          // 2*HPL

// ---------------------------------------------------------------------------
// Kernel A: spatial means of all xa / xb channels for every layer & batch.
// One 64-thread block per (l, b, ch) with ch in [0,64): ch<32 -> xa, else xb.
// ---------------------------------------------------------------------------
__global__ __launch_bounds__(64) void mean_kernel(const float* __restrict__ x,
                                                  float* __restrict__ meansA,
                                                  float* __restrict__ meansB) {
    const int lid = blockIdx.x;
    const int l  = lid / (B_ * 64);
    const int r  = lid - l * (B_ * 64);
    const int b  = r >> 6;
    const int ch = r & 63;
    const long chan = (ch < 32) ? ((long)l * HPL_ + ch)
                                : ((long)N_ + (long)l * HPL_ + (ch - 32));
    const float4* p4 = (const float4*)(x + ((long)b * 2 * N_ + chan) * HW_);
    const int t = threadIdx.x;
    float s = 0.f;
#pragma unroll
    for (int i = 0; i < 16; ++i) {
        float4 v = p4[i * 64 + t];
        s += (v.x + v.y) + (v.z + v.w);
    }
#pragma unroll
    for (int off = 32; off > 0; off >>= 1) s += __shfl_down(s, off);
    if (t == 0) {
        const float m = s * (1.0f / 4096.0f);
        if (ch < 32) meansA[(l * B_ + b) * 32 + ch] = m;
        else         meansB[(l * B_ + b) * 32 + (ch - 32)] = m;
    }
}

// ---------------------------------------------------------------------------
// Extract the (xa, xb) pair for this thread's 4 output-p's with compile-time
// cat[] indices (keeps cat in VGPRs — runtime indexing would spill to scratch).
// ---------------------------------------------------------------------------
template <int P0>
__device__ __forceinline__ void extract_mix(const float (&cat)[NCH_],
                                            float (&xa4)[4], float (&xb4)[4]) {
#pragma unroll
    for (int pp = 0; pp < 4; ++pp) {
        xa4[pp] = cat[3 * (P0 + pp)];
        xb4[pp] = cat[3 * (P0 + pp) + 1];
    }
}

// ---------------------------------------------------------------------------
// Layer kernel: grid = 1024 blocks x 256 threads (4 blocks/CU, >=12 waves/CU).
// blockIdx = ((b*32 + pg)*4 + s); block handles 128 pixels; each thread owns
// 1 pixel and 4 output-p's (split = s*2 + (tid>>7), p in [split*4, split*4+4)).
// ---------------------------------------------------------------------------
__global__ __launch_bounds__(256, 3) void layer_kernel(
    const float* __restrict__ x,
    const float* __restrict__ W1, const float* __restrict__ b1,
    const float* __restrict__ W2, const float* __restrict__ b2,
    const float* __restrict__ Wc, const float* __restrict__ bc,
    const float* __restrict__ meansA, const float* __restrict__ meansB,
    const float* __restrict__ sumsPrev, float* __restrict__ sumsOut,
    float* __restrict__ logits, float* __restrict__ coeff,
    float* __restrict__ waO, float* __restrict__ wbO,
    float* __restrict__ mixedO, int l) {
    __shared__ float s_gc[NCH_];
    __shared__ float s_hmid[HID_];
    __shared__ float s_gl[NO_];
    const int tid = threadIdx.x;
    const int blk = blockIdx.x;
    const int s   = blk & 3;
    const int pg  = (blk >> 2) & 31;
    const int b   = blk >> 7;

    // --- tiny MLP: gc -> hmid -> gl (redundant per block, ~trivial cost) ---
    if (tid < NCH_) {
        float g;
        if (tid < 32)       g = meansA[(l * B_ + b) * 32 + tid];
        else if (tid < 64)  g = meansB[(l * B_ + b) * 32 + (tid - 32)];
        else                g = (l == 0) ? 0.0f
                                 : sumsPrev[b * 32 + (tid - 64)] * (1.0f / 4096.0f);
        s_gc[tid] = g;
    }
    __syncthreads();
    if (tid < HID_) {
        const float* w1r = W1 + ((long)l * HID_ + tid) * NCH_;
        float h = b1[l * HID_ + tid];
#pragma unroll
        for (int c = 0; c < NCH_; ++c) h = __builtin_fmaf(s_gc[c], w1r[c], h);
        s_hmid[tid] = h / (1.0f + __expf(-h));   // silu
    }
    __syncthreads();
    if (tid < NO_) {
        const float* w2r = W2 + ((long)l * NO_ + tid) * HID_;
        float g = b2[l * NO_ + tid] + bc[l * NO_ + tid];  // fold bc into gl
#pragma unroll
        for (int j = 0; j < HID_; ++j) g = __builtin_fmaf(s_hmid[j], w2r[j], g);
        s_gl[tid] = g;
    }
    __syncthreads();

    const int split  = s * 2 + (tid >> 7);   // wave-uniform, [0,8)
    const int p0     = split << 2;           // 4 p's per thread
    const int pix    = (pg << 7) | (tid & 127);
    const int lane64 = tid & 63;

    // --- load the 96 cat values for this pixel into registers ---
    float cat[NCH_];
    const float* xa = x + ((long)b * 2 * N_ + (long)l * HPL_) * HW_ + pix;
    const float* xb = xa + (long)N_ * HW_;
#pragma unroll
    for (int c = 0; c < 32; ++c) cat[c] = xa[(long)c * HW_];
#pragma unroll
    for (int c = 0; c < 32; ++c) cat[32 + c] = xb[(long)c * HW_];
    if (l == 0) {
#pragma unroll
        for (int c = 0; c < 32; ++c) cat[64 + c] = 0.0f;
    } else {
        const float* pv = mixedO + ((long)b * L_ + (l - 1)) * HPL_ * (long)HW_ + pix;
#pragma unroll
        for (int c = 0; c < 32; ++c) cat[64 + c] = pv[(long)c * HW_];
    }

    // compile-time extraction of the mix inputs for this split
    float xa4[4], xb4[4];
    switch (split) {
        case 0:  extract_mix<0>(cat, xa4, xb4); break;
        case 1:  extract_mix<4 >(cat, xa4, xb4); break;
        case 2:  extract_mix<8 >(cat, xa4, xb4); break;
        case 3:  extract_mix<12>(cat, xa4, xb4); break;
        case 4:  extract_mix<16>(cat, xa4, xb4); break;
        case 5:  extract_mix<20>(cat, xa4, xb4); break;
        case 6:  extract_mix<24>(cat, xa4, xb4); break;
        default: extract_mix<28>(cat, xa4, xb4); break;
    }

    const float* wcL = Wc + (long)l * NO_ * NCH_ + (long)(2 * p0) * NCH_;
    const long base1 = ((long)b * L_ + l) * HPL_ * (long)HW_;
    const long base2 = 2 * base1;

#pragma unroll
    for (int pp = 0; pp < 4; ++pp) {
        const int p      = p0 + pp;                    // runtime wave-uniform
        const float* w0  = wcL + (2 * pp) * NCH_;      // wave-uniform addresses
        const float* w1r = w0 + NCH_;                  // -> scalar loads
        float a0 = 0.f, a1 = 0.f;
#pragma unroll
        for (int c = 0; c < NCH_; ++c) {
            a0 = __builtin_fmaf(cat[c], w0[c], a0);
            a1 = __builtin_fmaf(cat[c], w1r[c], a1);
        }
        const float lg0 = s_gl[2 * p] + a0;
        const float lg1 = s_gl[2 * p + 1] + a1;
        const float d   = lg1 - lg0;
        const float wbv = 1.0f / (1.0f + __expf(-d));
        const float wav = 1.0f - wbv;
        logits[base2 + (long)(2 * p) * HW_ + pix]     = lg0;
        logits[base2 + (long)(2 * p + 1) * HW_ + pix] = lg1;
        coeff [base2 + (long)(2 * p) * HW_ + pix]     = wav;
        coeff [base2 + (long)(2 * p + 1) * HW_ + pix] = wbv;
        waO[base1 + (long)p * HW_ + pix] = wav;
        wbO[base1 + (long)p * HW_ + pix] = wbv;
        const float xaa = xa4[pp];
        const float xbb = xb4[pp];
        const float mx  = __builtin_fmaf(wbv, xbb - xaa, xaa);
        mixedO[base1 + (long)p * HW_ + pix] = mx;
        // accumulate per-(b,p) spatial sum of mixed for next layer's gc
        float ss = mx;
#pragma unroll
        for (int off = 32; off > 0; off >>= 1) ss += __shfl_down(ss, off);
        if (lane64 == 0) atomicAdd(&sumsOut[b * 32 + p], ss);
    }
}

// ---------------------------------------------------------------------------
extern "C" void kernel_launch(void* const* d_in, const int* in_sizes, int n_in,
                              void* d_out, int out_size, void* d_ws, size_t ws_size,
                              hipStream_t stream) {
    const float* x  = (const float*)d_in[0];
    const float* W1 = (const float*)d_in[1];
    const float* b1 = (const float*)d_in[2];
    const float* W2 = (const float*)d_in[3];
    const float* b2 = (const float*)d_in[4];
    const float* Wc = (const float*)d_in[5];
    const float* bc = (const float*)d_in[6];

    float* out = (float*)d_out;
    const long S1 = (long)B_ * L_ * HPL_ * HW_;  // 25,165,824
    float* logits = out;                         // (B,L,32,2,64,64)  2*S1
    float* coeff  = out + 2 * S1;                // 2*S1
    float* waO    = out + 4 * S1;                // S1
    float* wbO    = out + 5 * S1;                // S1
    float* mixedO = out + 6 * S1;                // S1 (also the scan carry)

    float* sums   = (float*)d_ws;                // [L][B][32] mixed sums
    float* meansA = sums + (long)L_ * B_ * 32;   // [L][B][32]
    float* meansB = meansA + (long)L_ * B_ * 32; // [L][B][32]

    hipMemsetAsync(sums, 0, (size_t)L_ * B_ * 32 * sizeof(float), stream);

    hipLaunchKernelGGL(mean_kernel, dim3(L_ * B_ * 64), dim3(64), 0, stream,
                       x, meansA, meansB);

    for (int l = 0; l < L_; ++l) {
        const float* sp = (l == 0) ? sums : sums + (long)(l - 1) * B_ * 32;
        float* so = sums + (long)l * B_ * 32;
        hipLaunchKernelGGL(layer_kernel, dim3(1024), dim3(256), 0, stream,
                           x, W1, b1, W2, b2, Wc, bc, meansA, meansB, sp, so,
                           logits, coeff, waO, wbO, mixedO, l);
    }
}

// Round 2
// 2335.235 us; speedup vs baseline: 1.0323x; 1.0323x over previous
//
#include <hip/hip_runtime.h>

#define B_   8
#define L_   24
#define HPL_ 32
#define HID_ 10
#define N_   (L_*HPL_)   // 768
#define HW_  4096        // 64*64
#define NCH_ 96          // 3*HPL
#define NO_  64          // 2*HPL

// ---------------------------------------------------------------------------
// Kernel A: spatial means of all xa / xb channels for every layer & batch.
// One 64-thread block per (l, b, ch) with ch in [0,64): ch<32 -> xa, else xb.
// ---------------------------------------------------------------------------
__global__ __launch_bounds__(64) void mean_kernel(const float* __restrict__ x,
                                                  float* __restrict__ meansA,
                                                  float* __restrict__ meansB) {
    const int lid = blockIdx.x;
    const int l  = lid / (B_ * 64);
    const int r  = lid - l * (B_ * 64);
    const int b  = r >> 6;
    const int ch = r & 63;
    const long chan = (ch < 32) ? ((long)l * HPL_ + ch)
                                : ((long)N_ + (long)l * HPL_ + (ch - 32));
    const float4* p4 = (const float4*)(x + ((long)b * 2 * N_ + chan) * HW_);
    const int t = threadIdx.x;
    float s = 0.f;
#pragma unroll
    for (int i = 0; i < 16; ++i) {
        float4 v = p4[i * 64 + t];
        s += (v.x + v.y) + (v.z + v.w);
    }
#pragma unroll
    for (int off = 32; off > 0; off >>= 1) s += __shfl_down(s, off);
    if (t == 0) {
        const float m = s * (1.0f / 4096.0f);
        if (ch < 32) meansA[(l * B_ + b) * 32 + ch] = m;
        else         meansB[(l * B_ + b) * 32 + (ch - 32)] = m;
    }
}

// ---------------------------------------------------------------------------
// Extract the (xa, xb) pair for this thread's 4 output-p's with compile-time
// cat[] indices (keeps cat in VGPRs — runtime indexing would spill to scratch).
// ---------------------------------------------------------------------------
template <int P0>
__device__ __forceinline__ void extract_mix(const float (&cat)[NCH_],
                                            float (&xa4)[4], float (&xb4)[4]) {
#pragma unroll
    for (int pp = 0; pp < 4; ++pp) {
        xa4[pp] = cat[3 * (P0 + pp)];
        xb4[pp] = cat[3 * (P0 + pp) + 1];
    }
}

// ---------------------------------------------------------------------------
// Layer kernel: grid = 1024 blocks x 256 threads.
//   blockIdx.x = pg*8 + split :  split in [0,8) selects this block's 4 output
//   p's (p = split*4 .. split*4+3); pg in [0,128) selects 256 pixels.
// CRITICAL: split comes from blockIdx (SGPR-uniform), so the Wc row addresses
// are provably wave-uniform -> compiler emits s_load through the scalar cache
// and the dot loop is pure v_fma with SGPR weight operands. (Deriving split
// from tid>>7 made every weight read a per-lane vector load — the round-0/1
// bottleneck.)
// ---------------------------------------------------------------------------
__global__ __launch_bounds__(256, 2) void layer_kernel(
    const float* __restrict__ x,
    const float* __restrict__ W1, const float* __restrict__ b1,
    const float* __restrict__ W2, const float* __restrict__ b2,
    const float* __restrict__ Wc, const float* __restrict__ bc,
    const float* __restrict__ meansA, const float* __restrict__ meansB,
    const float* __restrict__ sumsPrev, float* __restrict__ sumsOut,
    float* __restrict__ logits, float* __restrict__ coeff,
    float* __restrict__ waO, float* __restrict__ wbO,
    float* __restrict__ mixedO, int l) {
    __shared__ float s_gc[NCH_];
    __shared__ float s_hmid[HID_];
    __shared__ float s_gl[NO_];
    const int tid   = threadIdx.x;
    const int blk   = blockIdx.x;
    const int split = blk & 7;            // SGPR -> provably uniform
    const int pg    = blk >> 3;           // [0,128)
    const int b     = pg >> 4;            // [0,8)
    const int pix   = ((pg & 15) << 8) | tid;   // 256 consecutive pixels

    // --- tiny MLP: gc -> hmid -> gl (redundant per block, ~trivial cost) ---
    if (tid < NCH_) {
        float g;
        if (tid < 32)       g = meansA[(l * B_ + b) * 32 + tid];
        else if (tid < 64)  g = meansB[(l * B_ + b) * 32 + (tid - 32)];
        else                g = (l == 0) ? 0.0f
                                 : sumsPrev[b * 32 + (tid - 64)] * (1.0f / 4096.0f);
        s_gc[tid] = g;
    }
    __syncthreads();
    if (tid < HID_) {
        const float* w1r = W1 + ((long)l * HID_ + tid) * NCH_;
        float h = b1[l * HID_ + tid];
#pragma unroll
        for (int c = 0; c < NCH_; ++c) h = __builtin_fmaf(s_gc[c], w1r[c], h);
        s_hmid[tid] = h / (1.0f + __expf(-h));   // silu
    }
    __syncthreads();
    if (tid < NO_) {
        const float* w2r = W2 + ((long)l * NO_ + tid) * HID_;
        float g = b2[l * NO_ + tid] + bc[l * NO_ + tid];  // fold bc into gl
#pragma unroll
        for (int j = 0; j < HID_; ++j) g = __builtin_fmaf(s_hmid[j], w2r[j], g);
        s_gl[tid] = g;
    }
    __syncthreads();

    const int p0     = split << 2;        // 4 p's per thread
    const int lane64 = tid & 63;

    // --- load the 96 cat values for this pixel into registers ---
    float cat[NCH_];
    const float* xa = x + ((long)b * 2 * N_ + (long)l * HPL_) * HW_ + pix;
    const float* xb = xa + (long)N_ * HW_;
#pragma unroll
    for (int c = 0; c < 32; ++c) cat[c] = xa[(long)c * HW_];
#pragma unroll
    for (int c = 0; c < 32; ++c) cat[32 + c] = xb[(long)c * HW_];
    if (l == 0) {
#pragma unroll
        for (int c = 0; c < 32; ++c) cat[64 + c] = 0.0f;
    } else {
        const float* pv = mixedO + ((long)b * L_ + (l - 1)) * HPL_ * (long)HW_ + pix;
#pragma unroll
        for (int c = 0; c < 32; ++c) cat[64 + c] = pv[(long)c * HW_];
    }

    // compile-time extraction of the mix inputs for this split (branch is
    // scalar: split is uniform)
    float xa4[4], xb4[4];
    switch (split) {
        case 0:  extract_mix<0>(cat, xa4, xb4); break;
        case 1:  extract_mix<4 >(cat, xa4, xb4); break;
        case 2:  extract_mix<8 >(cat, xa4, xb4); break;
        case 3:  extract_mix<12>(cat, xa4, xb4); break;
        case 4:  extract_mix<16>(cat, xa4, xb4); break;
        case 5:  extract_mix<20>(cat, xa4, xb4); break;
        case 6:  extract_mix<24>(cat, xa4, xb4); break;
        default: extract_mix<28>(cat, xa4, xb4); break;
    }

    const float* wcL = Wc + (long)l * NO_ * NCH_ + (long)(2 * p0) * NCH_;
    const long base1 = ((long)b * L_ + l) * HPL_ * (long)HW_;
    const long base2 = 2 * base1;

#pragma unroll
    for (int pp = 0; pp < 4; ++pp) {
        const int p      = p0 + pp;                    // uniform
        const float* w0  = wcL + (2 * pp) * NCH_;      // uniform -> s_load
        const float* w1r = w0 + NCH_;
        float a0 = 0.f, a1 = 0.f;
#pragma unroll
        for (int c = 0; c < NCH_; ++c) {
            a0 = __builtin_fmaf(cat[c], w0[c], a0);
            a1 = __builtin_fmaf(cat[c], w1r[c], a1);
        }
        const float lg0 = s_gl[2 * p] + a0;
        const float lg1 = s_gl[2 * p + 1] + a1;
        const float d   = lg1 - lg0;
        const float wbv = 1.0f / (1.0f + __expf(-d));
        const float wav = 1.0f - wbv;
        logits[base2 + (long)(2 * p) * HW_ + pix]     = lg0;
        logits[base2 + (long)(2 * p + 1) * HW_ + pix] = lg1;
        coeff [base2 + (long)(2 * p) * HW_ + pix]     = wav;
        coeff [base2 + (long)(2 * p + 1) * HW_ + pix] = wbv;
        waO[base1 + (long)p * HW_ + pix] = wav;
        wbO[base1 + (long)p * HW_ + pix] = wbv;
        const float xaa = xa4[pp];
        const float xbb = xb4[pp];
        const float mx  = __builtin_fmaf(wbv, xbb - xaa, xaa);
        mixedO[base1 + (long)p * HW_ + pix] = mx;
        // accumulate per-(b,p) spatial sum of mixed for next layer's gc
        float ss = mx;
#pragma unroll
        for (int off = 32; off > 0; off >>= 1) ss += __shfl_down(ss, off);
        if (lane64 == 0) atomicAdd(&sumsOut[b * 32 + p], ss);
    }
}

// ---------------------------------------------------------------------------
extern "C" void kernel_launch(void* const* d_in, const int* in_sizes, int n_in,
                              void* d_out, int out_size, void* d_ws, size_t ws_size,
                              hipStream_t stream) {
    const float* x  = (const float*)d_in[0];
    const float* W1 = (const float*)d_in[1];
    const float* b1 = (const float*)d_in[2];
    const float* W2 = (const float*)d_in[3];
    const float* b2 = (const float*)d_in[4];
    const float* Wc = (const float*)d_in[5];
    const float* bc = (const float*)d_in[6];

    float* out = (float*)d_out;
    const long S1 = (long)B_ * L_ * HPL_ * HW_;  // 25,165,824
    float* logits = out;                         // (B,L,32,2,64,64)  2*S1
    float* coeff  = out + 2 * S1;                // 2*S1
    float* waO    = out + 4 * S1;                // S1
    float* wbO    = out + 5 * S1;                // S1
    float* mixedO = out + 6 * S1;                // S1 (also the scan carry)

    float* sums   = (float*)d_ws;                // [L][B][32] mixed sums
    float* meansA = sums + (long)L_ * B_ * 32;   // [L][B][32]
    float* meansB = meansA + (long)L_ * B_ * 32; // [L][B][32]

    hipMemsetAsync(sums, 0, (size_t)L_ * B_ * 32 * sizeof(float), stream);

    hipLaunchKernelGGL(mean_kernel, dim3(L_ * B_ * 64), dim3(64), 0, stream,
                       x, meansA, meansB);

    for (int l = 0; l < L_; ++l) {
        const float* sp = (l == 0) ? sums : sums + (long)(l - 1) * B_ * 32;
        float* so = sums + (long)l * B_ * 32;
        hipLaunchKernelGGL(layer_kernel, dim3(1024), dim3(256), 0, stream,
                           x, W1, b1, W2, b2, Wc, bc, meansA, meansB, sp, so,
                           logits, coeff, waO, wbO, mixedO, l);
    }
}